// Round 7
// baseline (413.194 us; speedup 1.0000x reference)
//
#include <hip/hip_runtime.h>
#include <stdint.h>

typedef unsigned long long u64;
typedef float vf4 __attribute__((ext_vector_type(4)));

#define NB 32
#define N 512
#define MAXD 10
#define NW 8            // u64 words per 512-bit row
#define MAGIC 0x5EEDF00Du

// spread 8 bits -> u64 of 8 bytes each 0/1
__device__ __forceinline__ u64 spread8(unsigned b) {
    u64 x = (u64)(b * 0x01010101u);
    x |= x << 32;                       // broadcast byte to all 8 byte lanes
    x &= 0x8040201008040201ULL;         // byte i keeps bit i
    x += 0x7f7f7f7f7f7f7f7fULL;         // bit7 of byte i = (bit i was set)
    return (x >> 7) & 0x0101010101010101ULL;
}

// ---------------- single fused kernel ----------------
// grid: 256 blocks = (batch b, row-group g), 256 threads (4 waves).
// Phase 1 (pack): block (b,g) reads adjacency tile-row g of batch b ONCE
//   (8 tiles of 64x64 fp32), ballots row-words -> gA[b][i][w] (= bin&mask)
//   and column-words -> gB[b][j][w] (= (bin&mask)^T). Union over all 8 blocks
//   of a batch covers every (row, word) of both matrices exactly once.
// Handshake: per-block flag set to MAGIC (release, agent scope) after a
//   device fence; consumers spin-acquire on their batch's 8 flags. Robust to
//   any d_ws poison value (anything != MAGIC). Deadlock-free: LDS 67 KB ->
//   >=2 blocks/CU capacity, grid 256 <= 256 CUs => all blocks co-resident.
// Phase 2: sym row = gA|gB -> LDS plane-major bitset; per-source bitset BFS
//   with bit-sliced 4-bit distance counters; expand dist bytes -> emb rows,
//   268 MB coalesced float4 stream (the roofline term).
__global__ __launch_bounds__(256) void fused_spe(const float* __restrict__ adj,
                                                 const int* __restrict__ mask,
                                                 const float* __restrict__ emb,
                                                 vf4* __restrict__ out4,
                                                 u64* __restrict__ gA,
                                                 u64* __restrict__ gB,
                                                 unsigned* __restrict__ flags) {
    __shared__ u64 smemU[64 * 65];     // phase1: fp32 tile (64x65 f32); phase2: dist bytes
    __shared__ u64 adjT[NW * N];       // 32 KB, plane-major [w][j]
    __shared__ vf4 e4[(MAXD + 2) * 2];
    __shared__ unsigned char mAll[N];
    int blk = blockIdx.x;
    int b = blk >> 3, g = blk & 7;
    int t = threadIdx.x;
    int i0 = g * 64;
    float* tile = (float*)smemU;

    mAll[t] = (mask[b * N + t] != 0);
    mAll[t + 256] = (mask[b * N + t + 256] != 0);
    if (t < (MAXD + 2) * 2) e4[t] = ((const vf4*)emb)[t];
    const float* Ab = adj + (size_t)b * N * N;
    u64* gAb = gA + (size_t)b * N * NW;
    u64* gBb = gB + (size_t)b * N * NW;
    __syncthreads();

    int wv = t >> 6, lane = t & 63;
    for (int tj = 0; tj < 8; ++tj) {
        int j0 = tj * 64;
        #pragma unroll
        for (int s = 0; s < 4; ++s) {
            int idx = t + 256 * s;          // 0..1023 float4 slots of the 64x64 tile
            int r = idx >> 4, c4 = idx & 15;
            float4 va = *(const float4*)&Ab[(size_t)(i0 + r) * N + j0 + c4 * 4];
            int o = r * 65 + c4 * 4;
            tile[o] = va.x; tile[o + 1] = va.y; tile[o + 2] = va.z; tile[o + 3] = va.w;
        }
        __syncthreads();
        // row-words: bin&mask rows i0+r, word tj
        for (int s = 0; s < 16; ++s) {
            int r = wv * 16 + s;
            bool bit = (tile[r * 65 + lane] > 0.5f) && mAll[i0 + r] && mAll[j0 + lane];
            u64 word = __ballot(bit);
            if (lane == 0) gAb[(size_t)(i0 + r) * NW + tj] = word;
        }
        // col-words: (bin&mask)^T rows j0+c, word g  (stride-65 col read: 2-way, free)
        for (int s = 0; s < 16; ++s) {
            int c = wv * 16 + s;
            bool bit = (tile[lane * 65 + c] > 0.5f) && mAll[i0 + lane] && mAll[j0 + c];
            u64 word = __ballot(bit);
            if (lane == 0) gBb[(size_t)(j0 + c) * NW + g] = word;
        }
        __syncthreads();
    }
    // publish: device-scope fence, then release-store flag
    __threadfence();
    __syncthreads();
    if (t == 0)
        __hip_atomic_store(&flags[blk], MAGIC, __ATOMIC_RELEASE, __HIP_MEMORY_SCOPE_AGENT);
    // consume: wait for all 8 producers of batch b
    if (t < 8) {
        while (__hip_atomic_load(&flags[b * 8 + t], __ATOMIC_ACQUIRE,
                                 __HIP_MEMORY_SCOPE_AGENT) != MAGIC) {}
    }
    __syncthreads();
    __threadfence();   // acquire side: invalidate stale cached lines before data reads

    // ---- phase 2: load sym bitset (gA|gB), transpose to plane-major ----
    for (int q = t; q < N * NW; q += 256) {
        u64 w = gAb[q] | gBb[q];                 // coalesced
        adjT[(q & 7) * N + (q >> 3)] = w;
    }
    __syncthreads();                              // tile buffer now reusable as outB

    u64* outB = smemU;                            // dist bytes, pad-65 rows
    if (t < 64) {
        int i = i0 + t;
        bool mi = mAll[i] != 0;
        u64 c0[NW], c1[NW], c2[NW], c3[NW];
        #pragma unroll
        for (int w = 0; w < NW; ++w) { c0[w] = 0; c1[w] = 0; c2[w] = 0; c3[w] = 0; }

        if (mi) {
            u64 reach[NW] = {};
            u64 frontier[NW] = {};
            reach[i >> 6] = 1ULL << (i & 63);
            #pragma unroll
            for (int w = 0; w < NW; ++w) frontier[w] = reach[w];
            bool active = true;
            for (int k = 0; k <= MAXD; ++k) {
                // c += ~reach  (bit-sliced increment, 4-bit, max value 11)
                #pragma unroll
                for (int w = 0; w < NW; ++w) {
                    u64 u = ~reach[w];
                    u64 t0 = c0[w] & u; c0[w] ^= u;
                    u64 t1 = c1[w] & t0; c1[w] ^= t0;
                    u64 t2 = c2[w] & t1; c2[w] ^= t1;
                    c3[w] ^= t2;
                }
                if (k == MAXD) break;
                if (active) {
                    u64 acc[NW] = {};
                    bool sat = false;
                    for (int w = 0; w < NW && !sat; ++w) {
                        u64 f = frontier[w];
                        while (f) {
                            int j = (w << 6) + __builtin_ctzll(f);
                            f &= f - 1;
                            #pragma unroll
                            for (int e = 0; e < NW; ++e) acc[e] |= adjT[e * N + j];
                            u64 all = acc[0];
                            #pragma unroll
                            for (int e = 1; e < NW; ++e) all &= acc[e];
                            if (all == ~0ULL) { sat = true; break; }  // union saturated
                        }
                    }
                    bool any = false;
                    #pragma unroll
                    for (int w = 0; w < NW; ++w) {
                        u64 nf = acc[w] & ~reach[w];
                        frontier[w] = nf;
                        reach[w] |= nf;
                        any = any || (nf != 0);
                    }
                    active = any;
                }
            }
        } else {
            // invalid source row: all distances = 11 = 0b1011
            #pragma unroll
            for (int w = 0; w < NW; ++w) { c0[w] = ~0ULL; c1[w] = ~0ULL; c3[w] = ~0ULL; }
        }

        // bit-sliced counters -> dist bytes (8 per u64) into LDS
        #pragma unroll
        for (int w = 0; w < NW; ++w) {
            #pragma unroll
            for (int h = 0; h < 8; ++h) {
                unsigned b0 = (unsigned)(c0[w] >> (8 * h)) & 0xFF;
                unsigned b1 = (unsigned)(c1[w] >> (8 * h)) & 0xFF;
                unsigned b2 = (unsigned)(c2[w] >> (8 * h)) & 0xFF;
                unsigned b3 = (unsigned)(c3[w] >> (8 * h)) & 0xFF;
                outB[t * 65 + w * 8 + h] =
                    spread8(b0) | (spread8(b1) << 1) | (spread8(b2) << 2) | (spread8(b3) << 3);
            }
        }
    }
    __syncthreads();

    // ---- expansion: 64 rows x 1024 vf4 slots, all 4 waves, coalesced stores ----
    const unsigned char* db = (const unsigned char*)outB;
    vf4* outp = out4 + ((size_t)(b * N + i0)) * (N * 2);
    for (int r = 0; r < 64; ++r) {
        const unsigned char* drow = db + r * 65 * 8;
        vf4* rowp = outp + (size_t)r * (N * 2);
        #pragma unroll
        for (int s = 0; s < 4; ++s) {
            int q = t + 256 * s;      // 0..1023 vf4 slots in this row
            int j = q >> 1, h = q & 1;
            int d = drow[j];
            rowp[q] = e4[d * 2 + h];
        }
    }
}

extern "C" void kernel_launch(void* const* d_in, const int* in_sizes, int n_in,
                              void* d_out, int out_size, void* d_ws, size_t ws_size,
                              hipStream_t stream) {
    const float* adj = (const float*)d_in[0];
    const int* mask = (const int*)d_in[1];  // jnp bool -> int32 per harness convention
    const float* emb = (const float*)d_in[2];
    u64* gA = (u64*)d_ws;                                   // 1 MB
    u64* gB = (u64*)((char*)d_ws + (1u << 20));             // 1 MB
    unsigned* flags = (unsigned*)((char*)d_ws + (2u << 20)); // 1 KB
    fused_spe<<<dim3(NB * 8), 256, 0, stream>>>(adj, mask, emb, (vf4*)d_out,
                                                gA, gB, flags);
}

// Round 8
// 379.311 us; speedup vs baseline: 1.0893x; 1.0893x over previous
//
#include <hip/hip_runtime.h>
#include <stdint.h>

typedef unsigned long long u64;
typedef float vf4 __attribute__((ext_vector_type(4)));

#define NB 32
#define N 512
#define MAXD 10
#define NW 8  // u64 words per 512-bit row

// ---------------- K1: binarize + symmetrize + mask -> packed bitset ----------------
// grid: (36 tile-pairs, B), block 256. Tiles 64x64; __ballot builds one u64 word per row.
// NOTE: node_mask arrives as int32 (harness converts jnp bool -> int).
__global__ __launch_bounds__(256) void k1_pack(const float* __restrict__ adj,
                                               const int* __restrict__ mask,
                                               u64* __restrict__ gsym) {
    __shared__ float ldsA[64 * 65];  // +1 pad: row & column reads both conflict-free
    __shared__ float ldsB[64 * 65];
    __shared__ unsigned char mI[64], mJ[64];
    int p = blockIdx.x;
    int b = blockIdx.y;
    int ti = 0;
    while (p >= 8 - ti) { p -= 8 - ti; ++ti; }
    int tj = ti + p;
    int i0 = ti * 64, j0 = tj * 64;
    int t = threadIdx.x;
    if (t < 64) mI[t] = (mask[b * N + i0 + t] != 0);
    else if (t < 128) mJ[t - 64] = (mask[b * N + j0 + (t - 64)] != 0);
    const float* Ab = adj + (size_t)b * N * N;
    #pragma unroll
    for (int s = 0; s < 4; ++s) {
        int idx = t + 256 * s;          // 0..1023 float4 slots
        int r = idx >> 4, c4 = idx & 15;
        float4 va = *(const float4*)&Ab[(size_t)(i0 + r) * N + j0 + c4 * 4];
        float4 vb = *(const float4*)&Ab[(size_t)(j0 + r) * N + i0 + c4 * 4];
        int o = r * 65 + c4 * 4;
        ldsA[o] = va.x; ldsA[o + 1] = va.y; ldsA[o + 2] = va.z; ldsA[o + 3] = va.w;
        ldsB[o] = vb.x; ldsB[o + 1] = vb.y; ldsB[o + 2] = vb.z; ldsB[o + 3] = vb.w;
    }
    __syncthreads();
    int wave = t >> 6, lane = t & 63;
    // rows of tile ti, word tj
    for (int s = 0; s < 16; ++s) {
        int r = wave * 16 + s;
        bool bit = ((ldsA[r * 65 + lane] > 0.5f) || (ldsB[lane * 65 + r] > 0.5f))
                   && mI[r] && mJ[lane];
        u64 word = __ballot(bit);
        if (lane == 0) gsym[((size_t)b * N + i0 + r) * NW + tj] = word;
    }
    // rows of tile tj, word ti (diagonal tiles: benign identical double write)
    for (int s = 0; s < 16; ++s) {
        int r = wave * 16 + s;
        bool bit = ((ldsB[r * 65 + lane] > 0.5f) || (ldsA[lane * 65 + r] > 0.5f))
                   && mJ[r] && mI[lane];
        u64 word = __ballot(bit);
        if (lane == 0) gsym[((size_t)b * N + j0 + r) * NW + ti] = word;
    }
}

// spread 8 bits -> u64 of 8 bytes each 0/1
__device__ __forceinline__ u64 spread8(unsigned b) {
    u64 x = (u64)(b * 0x01010101u);
    x |= x << 32;                       // broadcast byte to all 8 byte lanes
    x &= 0x8040201008040201ULL;         // byte i keeps bit i
    x += 0x7f7f7f7f7f7f7f7fULL;         // bit7 of byte i = (bit i was set)
    return (x >> 7) & 0x0101010101010101ULL;
}

// ---------------- K2: bitset BFS, branch-free distance accumulation ----------------
// dist[j] = sum_{k=0..10} [j not in reach_k]. Bit-sliced 4-bit counters.
// grid: B*8 blocks, 64 threads (one thread per source row). Writes 8 MB dist bytes.
__global__ __launch_bounds__(64) void k2_bfs(const u64* __restrict__ gsym,
                                             const int* __restrict__ mask,
                                             u64* __restrict__ distg64) {
    __shared__ u64 adjT[NW * N];      // 32 KB, plane-major [w][j]
    __shared__ u64 outB[64 * 65];     // packed dist bytes, pad 65 breaks stride-128
    int blk = blockIdx.x;
    int b = blk >> 3;
    int r0 = (blk & 7) * 64;
    int t = threadIdx.x;
    const u64* gs = gsym + (size_t)b * N * NW;
    for (int q = t; q < N * NW; q += 64) {
        u64 w = gs[q];                           // coalesced
        adjT[(q & 7) * N + (q >> 3)] = w;        // transpose to plane-major
    }
    __syncthreads();

    int i = r0 + t;
    bool mi = mask[b * N + i] != 0;
    u64 c0[NW], c1[NW], c2[NW], c3[NW];
    #pragma unroll
    for (int w = 0; w < NW; ++w) { c0[w] = 0; c1[w] = 0; c2[w] = 0; c3[w] = 0; }

    if (mi) {
        u64 reach[NW] = {};
        u64 frontier[NW] = {};
        reach[i >> 6] = 1ULL << (i & 63);
        #pragma unroll
        for (int w = 0; w < NW; ++w) frontier[w] = reach[w];
        bool active = true;
        for (int k = 0; k <= MAXD; ++k) {
            // c += ~reach  (bit-sliced increment, 4-bit, max value 11)
            #pragma unroll
            for (int w = 0; w < NW; ++w) {
                u64 u = ~reach[w];
                u64 t0 = c0[w] & u; c0[w] ^= u;
                u64 t1 = c1[w] & t0; c1[w] ^= t0;
                u64 t2 = c2[w] & t1; c2[w] ^= t1;
                c3[w] ^= t2;
            }
            if (k == MAXD) break;
            if (active) {
                u64 acc[NW] = {};
                bool sat = false;
                for (int w = 0; w < NW && !sat; ++w) {
                    u64 f = frontier[w];
                    while (f) {
                        int j = (w << 6) + __builtin_ctzll(f);
                        f &= f - 1;
                        #pragma unroll
                        for (int e = 0; e < NW; ++e) acc[e] |= adjT[e * N + j];
                        u64 all = acc[0];
                        #pragma unroll
                        for (int e = 1; e < NW; ++e) all &= acc[e];
                        if (all == ~0ULL) { sat = true; break; }  // union saturated: exact
                    }
                }
                bool any = false;
                #pragma unroll
                for (int w = 0; w < NW; ++w) {
                    u64 nf = acc[w] & ~reach[w];
                    frontier[w] = nf;
                    reach[w] |= nf;
                    any = any || (nf != 0);
                }
                active = any;
            }
        }
    } else {
        // invalid source row: all distances = 11 = 0b1011
        #pragma unroll
        for (int w = 0; w < NW; ++w) { c0[w] = ~0ULL; c1[w] = ~0ULL; c3[w] = ~0ULL; }
    }

    // bit-sliced counters -> dist bytes (8 per u64), staged in LDS
    #pragma unroll
    for (int w = 0; w < NW; ++w) {
        #pragma unroll
        for (int h = 0; h < 8; ++h) {
            unsigned b0 = (unsigned)(c0[w] >> (8 * h)) & 0xFF;
            unsigned b1 = (unsigned)(c1[w] >> (8 * h)) & 0xFF;
            unsigned b2 = (unsigned)(c2[w] >> (8 * h)) & 0xFF;
            unsigned b3 = (unsigned)(c3[w] >> (8 * h)) & 0xFF;
            outB[t * 65 + w * 8 + h] =
                spread8(b0) | (spread8(b1) << 1) | (spread8(b2) << 2) | (spread8(b3) << 3);
        }
    }
    __syncthreads();
    // coalesced copy-out: row-major dist bytes, 64 u64 per row
    u64* dg = distg64 + (size_t)blk * 64 * 64;
    for (int q = t; q < 64 * 64; q += 64)
        dg[q] = outB[(q >> 6) * 65 + (q & 63)];
}

// ---------------- K3: high-occupancy grid-stride expansion ----------------
// 2048 blocks x 256 thr = 8 blocks/CU = 32 waves/CU. Per vf4 slot q:
//   d = dist[q>>1] (global ubyte, L2-hit, 32 consecutive bytes per wave)
//   out[q] = e4[d*2 + (q&1)]  (LDS b128, <=4 distinct addrs -> multicast)
// Stores: lane q -> consecutive 16B = perfectly coalesced 1 KB/wave-instr.
#define K3_THREADS (2048 * 256)
#define K3_SLOTS   ((size_t)NB * N * N * 2)     // 16,777,216 vf4
__global__ __launch_bounds__(256) void k3_expand(const unsigned char* __restrict__ dist,
                                                 const float* __restrict__ emb,
                                                 vf4* __restrict__ out4) {
    __shared__ vf4 e4[(MAXD + 2) * 2];
    int t = threadIdx.x;
    if (t < (MAXD + 2) * 2) e4[t] = ((const vf4*)emb)[t];
    __syncthreads();
    size_t gid = (size_t)blockIdx.x * 256 + t;
    #pragma unroll 4
    for (int it = 0; it < (int)(K3_SLOTS / K3_THREADS); ++it) {
        size_t q = gid + (size_t)it * K3_THREADS;
        unsigned d = dist[q >> 1];
        out4[q] = e4[d * 2 + (q & 1)];
    }
}

extern "C" void kernel_launch(void* const* d_in, const int* in_sizes, int n_in,
                              void* d_out, int out_size, void* d_ws, size_t ws_size,
                              hipStream_t stream) {
    const float* adj = (const float*)d_in[0];
    const int* mask = (const int*)d_in[1];  // jnp bool -> int32 per harness convention
    const float* emb = (const float*)d_in[2];
    u64* gsym = (u64*)d_ws;                                                 // 1 MB
    unsigned char* distg = (unsigned char*)d_ws + (size_t)NB * N * NW * 8;  // 8 MB
    k1_pack<<<dim3(36, NB), 256, 0, stream>>>(adj, mask, gsym);
    k2_bfs<<<dim3(NB * 8), 64, 0, stream>>>(gsym, mask, (u64*)distg);
    k3_expand<<<dim3(2048), 256, 0, stream>>>(distg, emb, (vf4*)d_out);
}